// Round 2
// baseline (155.664 us; speedup 1.0000x reference)
//
#include <hip/hip_runtime.h>

// SparseWindowedAttention: B=1, S=4096, E=768, H=12, hd=64, window=128
// Inputs fp32 (converted to bf16 in ws), output fp32. MFMA bf16, fp32 accum.
//
//   c0: fused fp32->bf16 convert (x, Wqkv, Wo), 4 chunks/thread (MLP=4)
//   k1: qkv GEMM 128x96, BK=64, A staged via swizzled DMA dbuf, B-operand
//       read DIRECT from global (weights L2-hot; splits traffic across the
//       LDS pipe and the L1/L2 pipe instead of funneling all through LDS).
//       Epilogue: V^T direct 8B stores, Q/K via LDS round-trip.
//   k2: windowed attention (unchanged)
//   k3: out = attn @ Wo^T + bo, 64x96, BK=64, same A-staged/B-direct split.

typedef __attribute__((ext_vector_type(8))) short short8;
typedef __attribute__((ext_vector_type(4))) short short4v;
typedef __attribute__((ext_vector_type(4))) float f32x4;

#define S_LEN 4096
#define EMB   768
#define NH    12
#define HD    64
#define QT    64
#define WMAX  128
#define NKT   20
#define QSCALE 0.18033688f   // 1/sqrt(64) * log2(e); softmax base-2

#if defined(__HIP_DEVICE_COMPILE__)
#define MFMA16(a, b, c) __builtin_amdgcn_mfma_f32_16x16x16bf16_1k(a, b, c, 0, 0, 0)
#else
#define MFMA16(a, b, c) (c)
#endif

__device__ __forceinline__ short f2bf(float f) {
    union { unsigned int i; float f; } c;
    c.f = f;
    unsigned int i = c.i;
    unsigned int r = (i + 0x7FFFu + ((i >> 16) & 1u)) >> 16;
    return (short)(unsigned short)r;
}

// fused fp32->bf16: segments [x | Wqkv | Wo]; 4 float4-chunks per thread
#define NX4  (S_LEN * EMB / 4)
#define NW4  (3 * EMB * EMB / 4)
#define NO4  (EMB * EMB / 4)
// NX4+NW4+NO4 = 1376256 = 1344 * 1024 exactly
__global__ __launch_bounds__(256) void convert_all(
    const float* __restrict__ x, const float* __restrict__ wqkv,
    const float* __restrict__ wo, short* __restrict__ xb,
    short* __restrict__ wqkvb, short* __restrict__ wob)
{
    int base = blockIdx.x * 1024 + threadIdx.x;
#pragma unroll
    for (int p = 0; p < 4; ++p) {
        int i = base + p * 256;
        const float* src; short* dst; int off;
        if (i < NX4)            { src = x;    dst = xb;    off = i; }
        else if (i < NX4 + NW4) { src = wqkv; dst = wqkvb; off = i - NX4; }
        else                    { src = wo;   dst = wob;   off = i - NX4 - NW4; }
        float4 v = ((const float4*)src)[off];
        short4v o = { f2bf(v.x), f2bf(v.y), f2bf(v.z), f2bf(v.w) };
        *(short4v*)(dst + (size_t)off * 4) = o;
    }
}

// ---------------------------------------------------------------------------
// QKV GEMM: C = A·B^T + bias, 128(M)x96(N), BK=64, grid 24x32=768 (3/CU).
// A: dbuf DMA into LDS with source-XOR swizzle (bank-balanced b128 reads at
// 128B row stride). B: direct global per-lane reads, reg-double-buffered one
// phase ahead (weights slab is L1/L2-hot). 12 barriers instead of 24.
// Epilogue: ty==2 (V) -> direct V^T[h][d][row] 8B stores; ty 0/1 (Q/K) ->
// LDS round-trip (Ct[128][100] shorts) then short8 coalesced stores.
// ---------------------------------------------------------------------------
__global__ __launch_bounds__(256) void gemm_qkv(
    const short* __restrict__ A, const short* __restrict__ B,
    const float* __restrict__ bias, short* __restrict__ Cv,
    int M, int N, int K)
{
    // As dbuf 2 x 128x64 shorts (32768 B); epilogue Ct[128][100] shorts
    // (25600 B) reuses the same region.
    __shared__ __align__(16) short smem[16384];
    short* As0 = smem;

    const int t = threadIdx.x;
    const int w = t >> 6, l = t & 63;
    const int quad = l >> 4, lane16 = l & 15;
    const int m0 = blockIdx.y * 128, n0 = blockIdx.x * 96;
    const int wm = (w >> 1) * 64, wn = (w & 1) * 48;

    f32x4 acc[4][3];
#pragma unroll
    for (int i = 0; i < 4; ++i)
#pragma unroll
        for (int j = 0; j < 3; ++j) acc[i][j] = (f32x4){0.f, 0.f, 0.f, 0.f};

    const int NKI = K >> 6;   // 12

    // B fragment base pointers: per-lane row, quad gives 16B sub-chunk.
    // Full-wave access = 16 rows x 64B contiguous per fragment.
    const short* Bp0 = B + (size_t)(n0 + wn +  0 + lane16) * K + quad * 8;
    const short* Bp1 = B + (size_t)(n0 + wn + 16 + lane16) * K + quad * 8;
    const short* Bp2 = B + (size_t)(n0 + wn + 32 + lane16) * K + quad * 8;

    auto stageA = [&](int ki, int b) {
        short* Asb = As0 + b * 8192;
#pragma unroll
        for (int i = 0; i < 4; ++i) {
            int c = i * 256 + t;              // 0..1023: 128 rows x 8 chunks
            int r = c >> 3, kc = c & 7;
            int g = kc ^ (r & 7);
#if defined(__HIP_DEVICE_COMPILE__) && __has_builtin(__builtin_amdgcn_global_load_lds)
            __builtin_amdgcn_global_load_lds(
                (const __attribute__((address_space(1))) void*)(A + (size_t)(m0 + r) * K + ki * 64 + g * 8),
                (__attribute__((address_space(3))) void*)(Asb + c * 8), 16, 0, 0);
#else
            *(short8*)(Asb + c * 8) = *(const short8*)(A + (size_t)(m0 + r) * K + ki * 64 + g * 8);
#endif
        }
    };

    short8 bA0, bA1, bA2, bB0, bB1, bB2;
    // preload B fragments for step 0, ks=0 (offset ki*64 + ks*32)
    bA0 = *(const short8*)(Bp0);
    bA1 = *(const short8*)(Bp1);
    bA2 = *(const short8*)(Bp2);
    stageA(0, 0);

    for (int kb = 0; kb < NKI; ++kb) {
        const int cur = kb & 1;
        __syncthreads();
        if (kb + 1 < NKI) stageA(kb + 1, cur ^ 1);

        const short* Asb = As0 + cur * 8192;

        // ---- ks = 0 ----
        short8 af[4];
#pragma unroll
        for (int mt = 0; mt < 4; ++mt) {
            int row = wm + mt * 16 + lane16;
            int slot = quad ^ (row & 7);
            af[mt] = *(const short8*)(Asb + row * 64 + slot * 8);
        }
        {   // prefetch B for ks=1 of this step
            size_t o = (size_t)kb * 64 + 32;
            bB0 = *(const short8*)(Bp0 + o);
            bB1 = *(const short8*)(Bp1 + o);
            bB2 = *(const short8*)(Bp2 + o);
        }
#pragma unroll
        for (int mt = 0; mt < 4; ++mt) {
            acc[mt][0] = __builtin_amdgcn_mfma_f32_16x16x32_bf16(af[mt], bA0, acc[mt][0], 0, 0, 0);
            acc[mt][1] = __builtin_amdgcn_mfma_f32_16x16x32_bf16(af[mt], bA1, acc[mt][1], 0, 0, 0);
            acc[mt][2] = __builtin_amdgcn_mfma_f32_16x16x32_bf16(af[mt], bA2, acc[mt][2], 0, 0, 0);
        }

        // ---- ks = 1 ----
#pragma unroll
        for (int mt = 0; mt < 4; ++mt) {
            int row = wm + mt * 16 + lane16;
            int slot = (4 + quad) ^ (row & 7);
            af[mt] = *(const short8*)(Asb + row * 64 + slot * 8);
        }
        {   // prefetch B for ks=0 of next step (dummy ki=0 on last iter)
            size_t o = (size_t)(kb + 1 < NKI ? kb + 1 : 0) * 64;
            bA0 = *(const short8*)(Bp0 + o);
            bA1 = *(const short8*)(Bp1 + o);
            bA2 = *(const short8*)(Bp2 + o);
        }
#pragma unroll
        for (int mt = 0; mt < 4; ++mt) {
            acc[mt][0] = __builtin_amdgcn_mfma_f32_16x16x32_bf16(af[mt], bB0, acc[mt][0], 0, 0, 0);
            acc[mt][1] = __builtin_amdgcn_mfma_f32_16x16x32_bf16(af[mt], bB1, acc[mt][1], 0, 0, 0);
            acc[mt][2] = __builtin_amdgcn_mfma_f32_16x16x32_bf16(af[mt], bB2, acc[mt][2], 0, 0, 0);
        }
    }

    __syncthreads();   // K-loop LDS reads done; smem free for epilogue tile
    short(*Ct)[100] = (short(*)[100])smem;   // pad 96->100: quads land 8 banks apart

#pragma unroll
    for (int nt = 0; nt < 3; ++nt) {
        int col = n0 + wn + nt * 16 + lane16;
        float bv = bias[col];
        int h = col / 192;
        int rem = col - h * 192;
        int ty = rem >> 6, d = rem & 63;
        if (ty == 2) {
            // V^T[h][d][row]: 4 consecutive rows per acc reg -> 8B store
            short* vt = Cv + ((size_t)2 * NH * S_LEN) * HD + ((size_t)h * HD + d) * S_LEN;
#pragma unroll
            for (int mt = 0; mt < 4; ++mt) {
                int row0 = m0 + wm + mt * 16 + quad * 4;
                short4v o = { f2bf(acc[mt][nt][0] + bv), f2bf(acc[mt][nt][1] + bv),
                              f2bf(acc[mt][nt][2] + bv), f2bf(acc[mt][nt][3] + bv) };
                *(short4v*)(vt + row0) = o;
            }
        } else {
            float s = (ty == 0) ? QSCALE : 1.f;
            int cl = wn + nt * 16 + lane16;   // col-local 0..95
#pragma unroll
            for (int mt = 0; mt < 4; ++mt) {
#pragma unroll
                for (int r = 0; r < 4; ++r)
                    Ct[wm + mt * 16 + quad * 4 + r][cl] = f2bf((acc[mt][nt][r] + bv) * s);
            }
        }
    }
    __syncthreads();

    // coalesced flush: 1536 short8-chunks (row 0..127, colgroup 0..11)
#pragma unroll
    for (int pass = 0; pass < 6; ++pass) {
        int c = pass * 256 + t;
        int row = c / 12, cg = c - row * 12;
        int col0 = n0 + cg * 8;               // 8-col group never straddles ty
        int h = col0 / 192;
        int rem = col0 - h * 192;
        int ty = rem >> 6;
        if (ty == 2) continue;                // V already stored directly
        int d0 = rem - ty * 64;
        short* dst = Cv + (((size_t)ty * NH + h) * S_LEN + (m0 + row)) * HD + d0;
        *(short8*)dst = *(const short8*)(&Ct[row][cg * 8]);
    }
}

// ---------------------------------------------------------------------------
// Windowed attention (unchanged). Q pre-scaled -> base-2 softmax. One 40960B
// LDS buffer: K (swizzled) for scores, then V^T for PV (DMA under softmax).
// ---------------------------------------------------------------------------
__global__ __launch_bounds__(256, 3) void attn_win(
    const short* __restrict__ qsplit, const int* __restrict__ wptr,
    short* __restrict__ attn_out)
{
    __shared__ __align__(16) short KS[320 * 64];   // 40960 B

    const int t = threadIdx.x;
    const int w = t >> 6, l = t & 63;
    const int quad = l >> 4, lane16 = l & 15;

    const int id = blockIdx.x;
    const int xcd = id & 7, j = id >> 3;
    const int h = j >> 3;
    const int q0 = ((xcd << 3) + (j & 7)) * QT;
    const int W = *wptr;
    const int kbase = q0 - WMAX;

    const short* Qh  = qsplit + (size_t)h * S_LEN * HD;
    const short* Kh  = qsplit + (size_t)(NH + h) * S_LEN * HD;
    const short* VtG = qsplit + (size_t)2 * NH * S_LEN * HD + (size_t)h * HD * S_LEN;

#pragma unroll
    for (int i = 0; i < 10; ++i) {
        int c = i * 256 + t;
        int r = c >> 3, gs = c & 7;
        int g = gs ^ (r & 7);
        int idx = min(max(kbase + r, 0), S_LEN - 1);
#if defined(__HIP_DEVICE_COMPILE__) && __has_builtin(__builtin_amdgcn_global_load_lds)
        __builtin_amdgcn_global_load_lds(
            (const __attribute__((address_space(1))) void*)(Kh + (size_t)idx * HD + g * 8),
            (__attribute__((address_space(3))) void*)(KS + c * 8), 16, 0, 0);
#else
        *(short8*)(KS + c * 8) = *(const short8*)(Kh + (size_t)idx * HD + g * 8);
#endif
    }
    const int qi = q0 + w * 16 + lane16;
    const short* qp = Qh + (size_t)qi * HD;
    short8 bq0 = *(const short8*)(qp + quad * 8);
    short8 bq1 = *(const short8*)(qp + 32 + quad * 8);

    __syncthreads();   // K resident

    f32x4 sc[NKT];
    const int d7 = lane16 & 7;
    const int s0 = (quad ^ d7) * 8;
    const int s1 = ((quad + 4) ^ d7) * 8;
#pragma unroll
    for (int kt = 0; kt < NKT; ++kt) {
        const short* kp = KS + (kt * 16 + lane16) * 64;
        short8 a0 = *(const short8*)(kp + s0);
        short8 a1 = *(const short8*)(kp + s1);
        f32x4 a = (f32x4){0.f, 0.f, 0.f, 0.f};
        a = __builtin_amdgcn_mfma_f32_16x16x32_bf16(a0, bq0, a, 0, 0, 0);
        a = __builtin_amdgcn_mfma_f32_16x16x32_bf16(a1, bq1, a, 0, 0, 0);
        sc[kt] = a;
    }

    __syncthreads();   // WAR: K reads done; KS free for V^T

#pragma unroll
    for (int i = 0; i < 10; ++i) {
        int c = i * 256 + t;
        int d = c / 40;
        int slot = c - d * 40;
        int sg = slot >> 3, s = slot & 7;
        int g = s ^ (d & 7);
        int key0 = kbase + sg * 64 + g * 8;
        key0 = min(max(key0, 0), S_LEN - 8);
#if defined(__HIP_DEVICE_COMPILE__) && __has_builtin(__builtin_amdgcn_global_load_lds)
        __builtin_amdgcn_global_load_lds(
            (const __attribute__((address_space(1))) void*)(VtG + (size_t)d * S_LEN + key0),
            (__attribute__((address_space(3))) void*)(KS + c * 8), 16, 0, 0);
#else
        *(short8*)(KS + c * 8) = *(const short8*)(VtG + (size_t)d * S_LEN + key0);
#endif
    }

    float m = -1e30f;
#pragma unroll
    for (int kt = 0; kt < NKT; ++kt) {
#pragma unroll
        for (int r = 0; r < 4; ++r) {
            int key = kbase + kt * 16 + quad * 4 + r;
            int dd = qi - key;
            int ad = dd < 0 ? -dd : dd;
            bool valid = ((unsigned)key < S_LEN) && (ad <= W);
            float s = valid ? sc[kt][r] : -1e30f;
            sc[kt][r] = s;
            m = fmaxf(m, s);
        }
    }
    m = fmaxf(m, __shfl_xor(m, 16, 64));
    m = fmaxf(m, __shfl_xor(m, 32, 64));

    float lsum = 0.f;
#pragma unroll
    for (int kt = 0; kt < NKT; ++kt) {
#pragma unroll
        for (int r = 0; r < 4; ++r) {
            float p = exp2f(sc[kt][r] - m);
            sc[kt][r] = p;
            lsum += p;
        }
    }
    lsum += __shfl_xor(lsum, 16, 64);
    lsum += __shfl_xor(lsum, 32, 64);
    const float rl = 1.f / fmaxf(lsum, 1e-30f);

    __syncthreads();   // V^T resident

    f32x4 oacc[4];
#pragma unroll
    for (int nt = 0; nt < 4; ++nt) oacc[nt] = (f32x4){0.f, 0.f, 0.f, 0.f};

#pragma unroll
    for (int kt = 0; kt < NKT; ++kt) {
        short4v pb = { f2bf(sc[kt][0]), f2bf(sc[kt][1]),
                       f2bf(sc[kt][2]), f2bf(sc[kt][3]) };
        int G = kt * 2 + (quad >> 1);
        int off = (G >> 3) * 64 + ((G & 7) ^ d7) * 8 + (quad & 1) * 4;
#pragma unroll
        for (int nt = 0; nt < 4; ++nt) {
            short4v va = *(const short4v*)(KS + (nt * 16 + lane16) * 320 + off);
            oacc[nt] = MFMA16(va, pb, oacc[nt]);
        }
    }

#pragma unroll
    for (int nt = 0; nt < 4; ++nt) {
        short4v ob = { f2bf(oacc[nt][0] * rl), f2bf(oacc[nt][1] * rl),
                       f2bf(oacc[nt][2] * rl), f2bf(oacc[nt][3] * rl) };
        *(short4v*)(attn_out + (size_t)qi * EMB + h * HD + nt * 16 + quad * 4) = ob;
    }
}

// ---------------------------------------------------------------------------
// Output projection GEMM: 64(M)x96(N) tile, BK=64, grid 8x64=512 (2/CU).
// A: dbuf DMA w/ source-XOR swizzle (unchanged). B (Wo): DIRECT global
// per-lane reads, reg-double-buffered — Wo is 1.2 MB, shared by all 64
// M-blocks, L1/L2-hot. Halves staged DMA and LDS traffic.
// Epilogue via LDS round-trip (Ct[64][100] fp32) -> float4 coalesced stores.
// ---------------------------------------------------------------------------
__global__ __launch_bounds__(256) void gemm_out96(
    const short* __restrict__ A, const short* __restrict__ B,
    const float* __restrict__ bias, float* __restrict__ C,
    int M, int N, int K)
{
    // As dbuf 2 x 64x64 shorts (16384 B); epilogue Ct[64][100] fp32 (25600 B)
    __shared__ __align__(16) short smem[12800];
    short* As0 = smem;

    const int t = threadIdx.x;
    const int w = t >> 6, l = t & 63;
    const int quad = l >> 4, lane16 = l & 15;
    const int m0 = blockIdx.y * 64, n0 = blockIdx.x * 96;
    const int wm = (w >> 1) * 32, wn = (w & 1) * 48;

    f32x4 acc[2][3];
#pragma unroll
    for (int i = 0; i < 2; ++i)
#pragma unroll
        for (int j = 0; j < 3; ++j) acc[i][j] = (f32x4){0.f, 0.f, 0.f, 0.f};

    const int NKI = K >> 6;   // 12

    const short* Bp0 = B + (size_t)(n0 + wn +  0 + lane16) * K + quad * 8;
    const short* Bp1 = B + (size_t)(n0 + wn + 16 + lane16) * K + quad * 8;
    const short* Bp2 = B + (size_t)(n0 + wn + 32 + lane16) * K + quad * 8;

    auto stageA = [&](int ki, int b) {
        short* Asb = As0 + b * 4096;
#pragma unroll
        for (int i = 0; i < 2; ++i) {
            int c = i * 256 + t;              // 0..511: 64 rows x 8 chunks
            int r = c >> 3, kc = c & 7;
            int g = kc ^ (r & 7);
#if defined(__HIP_DEVICE_COMPILE__) && __has_builtin(__builtin_amdgcn_global_load_lds)
            __builtin_amdgcn_global_load_lds(
                (const __attribute__((address_space(1))) void*)(A + (size_t)(m0 + r) * K + ki * 64 + g * 8),
                (__attribute__((address_space(3))) void*)(Asb + c * 8), 16, 0, 0);
#else
            *(short8*)(Asb + c * 8) = *(const short8*)(A + (size_t)(m0 + r) * K + ki * 64 + g * 8);
#endif
        }
    };

    short8 bA0, bA1, bA2, bB0, bB1, bB2;
    bA0 = *(const short8*)(Bp0);
    bA1 = *(const short8*)(Bp1);
    bA2 = *(const short8*)(Bp2);
    stageA(0, 0);

    for (int kb = 0; kb < NKI; ++kb) {
        const int cur = kb & 1;
        __syncthreads();
        if (kb + 1 < NKI) stageA(kb + 1, cur ^ 1);

        const short* Asb = As0 + cur * 4096;

        // ---- ks = 0 ----
        short8 af[2];
#pragma unroll
        for (int mt = 0; mt < 2; ++mt) {
            int row = wm + mt * 16 + lane16;
            int slot = quad ^ (row & 7);
            af[mt] = *(const short8*)(Asb + row * 64 + slot * 8);
        }
        {
            size_t o = (size_t)kb * 64 + 32;
            bB0 = *(const short8*)(Bp0 + o);
            bB1 = *(const short8*)(Bp1 + o);
            bB2 = *(const short8*)(Bp2 + o);
        }
#pragma unroll
        for (int mt = 0; mt < 2; ++mt) {
            acc[mt][0] = __builtin_amdgcn_mfma_f32_16x16x32_bf16(af[mt], bA0, acc[mt][0], 0, 0, 0);
            acc[mt][1] = __builtin_amdgcn_mfma_f32_16x16x32_bf16(af[mt], bA1, acc[mt][1], 0, 0, 0);
            acc[mt][2] = __builtin_amdgcn_mfma_f32_16x16x32_bf16(af[mt], bA2, acc[mt][2], 0, 0, 0);
        }

        // ---- ks = 1 ----
#pragma unroll
        for (int mt = 0; mt < 2; ++mt) {
            int row = wm + mt * 16 + lane16;
            int slot = (4 + quad) ^ (row & 7);
            af[mt] = *(const short8*)(Asb + row * 64 + slot * 8);
        }
        {
            size_t o = (size_t)(kb + 1 < NKI ? kb + 1 : 0) * 64;
            bA0 = *(const short8*)(Bp0 + o);
            bA1 = *(const short8*)(Bp1 + o);
            bA2 = *(const short8*)(Bp2 + o);
        }
#pragma unroll
        for (int mt = 0; mt < 2; ++mt) {
            acc[mt][0] = __builtin_amdgcn_mfma_f32_16x16x32_bf16(af[mt], bB0, acc[mt][0], 0, 0, 0);
            acc[mt][1] = __builtin_amdgcn_mfma_f32_16x16x32_bf16(af[mt], bB1, acc[mt][1], 0, 0, 0);
            acc[mt][2] = __builtin_amdgcn_mfma_f32_16x16x32_bf16(af[mt], bB2, acc[mt][2], 0, 0, 0);
        }
    }

    __syncthreads();   // K-loop LDS reads done
    float(*Ct)[100] = (float(*)[100])smem;   // 64x100 fp32, pad kills conflicts

#pragma unroll
    for (int nt = 0; nt < 3; ++nt) {
        int cl = wn + nt * 16 + lane16;
        float bv = bias[n0 + cl];
#pragma unroll
        for (int mt = 0; mt < 2; ++mt) {
#pragma unroll
            for (int r = 0; r < 4; ++r)
                Ct[wm + mt * 16 + quad * 4 + r][cl] = acc[mt][nt][r] + bv;
        }
    }
    __syncthreads();

    // coalesced flush: 1536 float4-chunks (row 0..63, colgroup 0..23)
#pragma unroll
    for (int pass = 0; pass < 6; ++pass) {
        int c = pass * 256 + t;
        int row = c / 24, cg = c - row * 24;
        float4 v = { Ct[row][cg * 4], Ct[row][cg * 4 + 1],
                     Ct[row][cg * 4 + 2], Ct[row][cg * 4 + 3] };
        *(float4*)(C + (size_t)(m0 + row) * N + n0 + cg * 4) = v;
    }
}

extern "C" void kernel_launch(void* const* d_in, const int* in_sizes, int n_in,
                              void* d_out, int out_size, void* d_ws, size_t ws_size,
                              hipStream_t stream) {
    const float* x    = (const float*)d_in[0];
    const float* Wqkv = (const float*)d_in[1];
    const float* bqkv = (const float*)d_in[2];
    const float* Wo   = (const float*)d_in[3];
    const float* bo   = (const float*)d_in[4];
    const int*   wptr = (const int*)d_in[5];

    float* out = (float*)d_out;

    short* xb     = (short*)d_ws;
    short* wqkvb  = xb     + (size_t)S_LEN * EMB;
    short* wob    = wqkvb  + (size_t)3 * EMB * EMB;
    short* qsplit = wob    + (size_t)EMB * EMB;          // Q|K row-major, V^T
    short* attn   = qsplit + (size_t)3 * NH * S_LEN * HD;

    dim3 blk(256);
    convert_all<<<dim3((NX4 + NW4 + NO4) / 1024), blk, 0, stream>>>(
        x, Wqkv, Wo, xb, wqkvb, wob);
    gemm_qkv<<<dim3(2304 / 96, S_LEN / 128), blk, 0, stream>>>(
        xb, wqkvb, bqkv, qsplit, S_LEN, 2304, EMB);
    attn_win<<<dim3(S_LEN / QT * NH), blk, 0, stream>>>(qsplit, wptr, attn);
    gemm_out96<<<dim3(EMB / 96, S_LEN / 64), blk, 0, stream>>>(
        attn, wob, bo, out, S_LEN, EMB, EMB);
}

// Round 4
// 132.900 us; speedup vs baseline: 1.1713x; 1.1713x over previous
//
#include <hip/hip_runtime.h>

// SparseWindowedAttention: B=1, S=4096, E=768, H=12, hd=64, window=128
// Inputs fp32 (converted to bf16 in ws), output fp32. MFMA bf16, fp32 accum.
//
//   c0: fused fp32->bf16 convert (x, Wqkv, Wo), 4 chunks/thread (MLP=4)
//   k1: qkv GEMM 128x96 (768 blocks = 3/CU), dbuf DMA; epilogue: V^T direct
//       8B stores, Q/K via LDS-round-trip -> 16B/lane coalesced stores
//       [R2 lesson: B-direct-from-global regressed 20us — per-lane B loads
//        share vmcnt with staging DMA, serializing the dbuf pipeline. Keep
//        both operands LDS-staged.]
//   k2: windowed attention + T5 s_setprio around MFMA clusters (independent
//       blocks at mixed phases, 3/CU — m191 regime where setprio pays)
//   k3: out = attn @ Wo^T + bo, 64x96 dbuf GEMM; LDS-round-trip fp32 epilogue

typedef __attribute__((ext_vector_type(8))) short short8;
typedef __attribute__((ext_vector_type(4))) short short4v;
typedef __attribute__((ext_vector_type(4))) float f32x4;

#define S_LEN 4096
#define EMB   768
#define NH    12
#define HD    64
#define QT    64
#define WMAX  128
#define NKT   20
#define QSCALE 0.18033688f   // 1/sqrt(64) * log2(e); softmax base-2

#if defined(__HIP_DEVICE_COMPILE__)
#define MFMA16(a, b, c) __builtin_amdgcn_mfma_f32_16x16x16bf16_1k(a, b, c, 0, 0, 0)
#define SETPRIO(x) __builtin_amdgcn_s_setprio(x)
#else
#define MFMA16(a, b, c) (c)
#define SETPRIO(x)
#endif

__device__ __forceinline__ short f2bf(float f) {
    union { unsigned int i; float f; } c;
    c.f = f;
    unsigned int i = c.i;
    unsigned int r = (i + 0x7FFFu + ((i >> 16) & 1u)) >> 16;
    return (short)(unsigned short)r;
}

// fused fp32->bf16: segments [x | Wqkv | Wo]; 4 float4-chunks per thread
#define NX4  (S_LEN * EMB / 4)
#define NW4  (3 * EMB * EMB / 4)
#define NO4  (EMB * EMB / 4)
// NX4+NW4+NO4 = 1376256 = 1344 * 1024 exactly
__global__ __launch_bounds__(256) void convert_all(
    const float* __restrict__ x, const float* __restrict__ wqkv,
    const float* __restrict__ wo, short* __restrict__ xb,
    short* __restrict__ wqkvb, short* __restrict__ wob)
{
    int base = blockIdx.x * 1024 + threadIdx.x;
#pragma unroll
    for (int p = 0; p < 4; ++p) {
        int i = base + p * 256;
        const float* src; short* dst; int off;
        if (i < NX4)            { src = x;    dst = xb;    off = i; }
        else if (i < NX4 + NW4) { src = wqkv; dst = wqkvb; off = i - NX4; }
        else                    { src = wo;   dst = wob;   off = i - NX4 - NW4; }
        float4 v = ((const float4*)src)[off];
        short4v o = { f2bf(v.x), f2bf(v.y), f2bf(v.z), f2bf(v.w) };
        *(short4v*)(dst + (size_t)off * 4) = o;
    }
}

// ---------------------------------------------------------------------------
// QKV GEMM: C = A·B^T + bias, 128(M)x96(N), BK=32, dbuf DMA, grid 24x32=768.
// Epilogue: ty==2 (V) -> direct V^T[h][d][row] 8B stores; ty 0/1 (Q/K) ->
// LDS round-trip (Ct[128][100] shorts, pad kills 8-way write conflicts) then
// short8 coalesced stores. Q pre-scaled by QSCALE.
// ---------------------------------------------------------------------------
__global__ __launch_bounds__(256) void gemm_qkv(
    const short* __restrict__ A, const short* __restrict__ B,
    const float* __restrict__ bias, short* __restrict__ Cv,
    int M, int N, int K)
{
    // unified LDS: As 2x4096, Bs 2x3072 shorts (28 KB); epilogue reuses it
    // as Ct[128][100] shorts (25.6 KB)
    __shared__ __align__(16) short smem[2 * 4096 + 2 * 3072];
    short* As0 = smem;
    short* Bs0 = smem + 2 * 4096;

    const int t = threadIdx.x;
    const int w = t >> 6, l = t & 63;
    const int quad = l >> 4, lane16 = l & 15;
    const int m0 = blockIdx.y * 128, n0 = blockIdx.x * 96;
    const int wm = (w >> 1) * 64, wn = (w & 1) * 48;

    f32x4 acc[4][3];
#pragma unroll
    for (int i = 0; i < 4; ++i)
#pragma unroll
        for (int j = 0; j < 3; ++j) acc[i][j] = (f32x4){0.f, 0.f, 0.f, 0.f};

    const int NKI = K >> 5;   // 24

    auto stage = [&](int ki, int b) {
        short* Asb = As0 + b * 4096;
        short* Bsb = Bs0 + b * 3072;
#pragma unroll
        for (int i = 0; i < 4; ++i) {
            int c = i * 256 + t;              // 0..1023; 896 used
            if (c < 512) {
                int r = c >> 2, kc = c & 3;
#if defined(__HIP_DEVICE_COMPILE__) && __has_builtin(__builtin_amdgcn_global_load_lds)
                __builtin_amdgcn_global_load_lds(
                    (const __attribute__((address_space(1))) void*)(A + (size_t)(m0 + r) * K + ki * 32 + kc * 8),
                    (__attribute__((address_space(3))) void*)(Asb + c * 8), 16, 0, 0);
#else
                *(short8*)(Asb + c * 8) = *(const short8*)(A + (size_t)(m0 + r) * K + ki * 32 + kc * 8);
#endif
            } else if (c < 896) {
                int cb = c - 512;
                int r = cb >> 2, kc = cb & 3;
#if defined(__HIP_DEVICE_COMPILE__) && __has_builtin(__builtin_amdgcn_global_load_lds)
                __builtin_amdgcn_global_load_lds(
                    (const __attribute__((address_space(1))) void*)(B + (size_t)(n0 + r) * K + ki * 32 + kc * 8),
                    (__attribute__((address_space(3))) void*)(Bsb + cb * 8), 16, 0, 0);
#else
                *(short8*)(Bsb + cb * 8) = *(const short8*)(B + (size_t)(n0 + r) * K + ki * 32 + kc * 8);
#endif
            }
        }
    };

    stage(0, 0);
    for (int kb = 0; kb < NKI; ++kb) {
        const int cur = kb & 1;
        __syncthreads();
        if (kb + 1 < NKI) stage(kb + 1, cur ^ 1);

        const short* Asb = As0 + cur * 4096;
        const short* Bsb = Bs0 + cur * 3072;
        short8 af[4], bfr[3];
#pragma unroll
        for (int mt = 0; mt < 4; ++mt)
            af[mt] = *(const short8*)(Asb + (wm + mt * 16 + lane16) * 32 + quad * 8);
#pragma unroll
        for (int nt = 0; nt < 3; ++nt)
            bfr[nt] = *(const short8*)(Bsb + (wn + nt * 16 + lane16) * 32 + quad * 8);
#pragma unroll
        for (int mt = 0; mt < 4; ++mt)
#pragma unroll
            for (int nt = 0; nt < 3; ++nt)
                acc[mt][nt] = __builtin_amdgcn_mfma_f32_16x16x32_bf16(
                    af[mt], bfr[nt], acc[mt][nt], 0, 0, 0);
    }

    __syncthreads();   // K-loop LDS reads done; smem free for epilogue tile
    short(*Ct)[100] = (short(*)[100])smem;   // pad 96->100: quads land 8 banks apart

#pragma unroll
    for (int nt = 0; nt < 3; ++nt) {
        int col = n0 + wn + nt * 16 + lane16;
        float bv = bias[col];
        int h = col / 192;
        int rem = col - h * 192;
        int ty = rem >> 6, d = rem & 63;
        if (ty == 2) {
            // V^T[h][d][row]: 4 consecutive rows per acc reg -> 8B store
            short* vt = Cv + ((size_t)2 * NH * S_LEN) * HD + ((size_t)h * HD + d) * S_LEN;
#pragma unroll
            for (int mt = 0; mt < 4; ++mt) {
                int row0 = m0 + wm + mt * 16 + quad * 4;
                short4v o = { f2bf(acc[mt][nt][0] + bv), f2bf(acc[mt][nt][1] + bv),
                              f2bf(acc[mt][nt][2] + bv), f2bf(acc[mt][nt][3] + bv) };
                *(short4v*)(vt + row0) = o;
            }
        } else {
            float s = (ty == 0) ? QSCALE : 1.f;
            int cl = wn + nt * 16 + lane16;   // col-local 0..95
#pragma unroll
            for (int mt = 0; mt < 4; ++mt) {
#pragma unroll
                for (int r = 0; r < 4; ++r)
                    Ct[wm + mt * 16 + quad * 4 + r][cl] = f2bf((acc[mt][nt][r] + bv) * s);
            }
        }
    }
    __syncthreads();

    // coalesced flush: 1536 short8-chunks (row 0..127, colgroup 0..11)
#pragma unroll
    for (int pass = 0; pass < 6; ++pass) {
        int c = pass * 256 + t;
        int row = c / 12, cg = c - row * 12;
        int col0 = n0 + cg * 8;               // 8-col group never straddles ty
        int h = col0 / 192;
        int rem = col0 - h * 192;
        int ty = rem >> 6;
        if (ty == 2) continue;                // V already stored directly
        int d0 = rem - ty * 64;
        short* dst = Cv + (((size_t)ty * NH + h) * S_LEN + (m0 + row)) * HD + d0;
        *(short8*)dst = *(const short8*)(&Ct[row][cg * 8]);
    }
}

// ---------------------------------------------------------------------------
// Windowed attention. Q pre-scaled -> base-2 softmax. One 40960B LDS buffer:
// K (swizzled) for scores, then V^T for PV (DMA under softmax). T5 setprio
// around both MFMA clusters: 3 independent blocks/CU at different phases,
// scheduler favors MFMA-phase waves over DMA/softmax-phase waves (m191).
// ---------------------------------------------------------------------------
__global__ __launch_bounds__(256, 3) void attn_win(
    const short* __restrict__ qsplit, const int* __restrict__ wptr,
    short* __restrict__ attn_out)
{
    __shared__ __align__(16) short KS[320 * 64];   // 40960 B

    const int t = threadIdx.x;
    const int w = t >> 6, l = t & 63;
    const int quad = l >> 4, lane16 = l & 15;

    const int id = blockIdx.x;
    const int xcd = id & 7, j = id >> 3;
    const int h = j >> 3;
    const int q0 = ((xcd << 3) + (j & 7)) * QT;
    const int W = *wptr;
    const int kbase = q0 - WMAX;

    const short* Qh  = qsplit + (size_t)h * S_LEN * HD;
    const short* Kh  = qsplit + (size_t)(NH + h) * S_LEN * HD;
    const short* VtG = qsplit + (size_t)2 * NH * S_LEN * HD + (size_t)h * HD * S_LEN;

#pragma unroll
    for (int i = 0; i < 10; ++i) {
        int c = i * 256 + t;
        int r = c >> 3, gs = c & 7;
        int g = gs ^ (r & 7);
        int idx = min(max(kbase + r, 0), S_LEN - 1);
#if defined(__HIP_DEVICE_COMPILE__) && __has_builtin(__builtin_amdgcn_global_load_lds)
        __builtin_amdgcn_global_load_lds(
            (const __attribute__((address_space(1))) void*)(Kh + (size_t)idx * HD + g * 8),
            (__attribute__((address_space(3))) void*)(KS + c * 8), 16, 0, 0);
#else
        *(short8*)(KS + c * 8) = *(const short8*)(Kh + (size_t)idx * HD + g * 8);
#endif
    }
    const int qi = q0 + w * 16 + lane16;
    const short* qp = Qh + (size_t)qi * HD;
    short8 bq0 = *(const short8*)(qp + quad * 8);
    short8 bq1 = *(const short8*)(qp + 32 + quad * 8);

    __syncthreads();   // K resident

    f32x4 sc[NKT];
    const int d7 = lane16 & 7;
    const int s0 = (quad ^ d7) * 8;
    const int s1 = ((quad + 4) ^ d7) * 8;
    SETPRIO(1);
#pragma unroll
    for (int kt = 0; kt < NKT; ++kt) {
        const short* kp = KS + (kt * 16 + lane16) * 64;
        short8 a0 = *(const short8*)(kp + s0);
        short8 a1 = *(const short8*)(kp + s1);
        f32x4 a = (f32x4){0.f, 0.f, 0.f, 0.f};
        a = __builtin_amdgcn_mfma_f32_16x16x32_bf16(a0, bq0, a, 0, 0, 0);
        a = __builtin_amdgcn_mfma_f32_16x16x32_bf16(a1, bq1, a, 0, 0, 0);
        sc[kt] = a;
    }
    SETPRIO(0);

    __syncthreads();   // WAR: K reads done; KS free for V^T

#pragma unroll
    for (int i = 0; i < 10; ++i) {
        int c = i * 256 + t;
        int d = c / 40;
        int slot = c - d * 40;
        int sg = slot >> 3, s = slot & 7;
        int g = s ^ (d & 7);
        int key0 = kbase + sg * 64 + g * 8;
        key0 = min(max(key0, 0), S_LEN - 8);
#if defined(__HIP_DEVICE_COMPILE__) && __has_builtin(__builtin_amdgcn_global_load_lds)
        __builtin_amdgcn_global_load_lds(
            (const __attribute__((address_space(1))) void*)(VtG + (size_t)d * S_LEN + key0),
            (__attribute__((address_space(3))) void*)(KS + c * 8), 16, 0, 0);
#else
        *(short8*)(KS + c * 8) = *(const short8*)(VtG + (size_t)d * S_LEN + key0);
#endif
    }

    float m = -1e30f;
#pragma unroll
    for (int kt = 0; kt < NKT; ++kt) {
#pragma unroll
        for (int r = 0; r < 4; ++r) {
            int key = kbase + kt * 16 + quad * 4 + r;
            int dd = qi - key;
            int ad = dd < 0 ? -dd : dd;
            bool valid = ((unsigned)key < S_LEN) && (ad <= W);
            float s = valid ? sc[kt][r] : -1e30f;
            sc[kt][r] = s;
            m = fmaxf(m, s);
        }
    }
    m = fmaxf(m, __shfl_xor(m, 16, 64));
    m = fmaxf(m, __shfl_xor(m, 32, 64));

    float lsum = 0.f;
#pragma unroll
    for (int kt = 0; kt < NKT; ++kt) {
#pragma unroll
        for (int r = 0; r < 4; ++r) {
            float p = exp2f(sc[kt][r] - m);
            sc[kt][r] = p;
            lsum += p;
        }
    }
    lsum += __shfl_xor(lsum, 16, 64);
    lsum += __shfl_xor(lsum, 32, 64);
    const float rl = 1.f / fmaxf(lsum, 1e-30f);

    __syncthreads();   // V^T resident

    f32x4 oacc[4];
#pragma unroll
    for (int nt = 0; nt < 4; ++nt) oacc[nt] = (f32x4){0.f, 0.f, 0.f, 0.f};

    SETPRIO(1);
#pragma unroll
    for (int kt = 0; kt < NKT; ++kt) {
        short4v pb = { f2bf(sc[kt][0]), f2bf(sc[kt][1]),
                       f2bf(sc[kt][2]), f2bf(sc[kt][3]) };
        int G = kt * 2 + (quad >> 1);
        int off = (G >> 3) * 64 + ((G & 7) ^ d7) * 8 + (quad & 1) * 4;
#pragma unroll
        for (int nt = 0; nt < 4; ++nt) {
            short4v va = *(const short4v*)(KS + (nt * 16 + lane16) * 320 + off);
            oacc[nt] = MFMA16(va, pb, oacc[nt]);
        }
    }
    SETPRIO(0);

#pragma unroll
    for (int nt = 0; nt < 4; ++nt) {
        short4v ob = { f2bf(oacc[nt][0] * rl), f2bf(oacc[nt][1] * rl),
                       f2bf(oacc[nt][2] * rl), f2bf(oacc[nt][3] * rl) };
        *(short4v*)(attn_out + (size_t)qi * EMB + h * HD + nt * 16 + quad * 4) = ob;
    }
}

// ---------------------------------------------------------------------------
// Output projection GEMM: 64(M)x96(N) tile, BK=64, dbuf DMA w/ source-XOR
// swizzle. Grid 8x64 = 512 blocks (2/CU). Per wave: 32x48 sub-tile, acc 2x3;
// 12 MFMA : 10 ds_read_b128 per K-iter (-17% LDS bytes/FLOP vs 64x64).
// Epilogue via LDS round-trip (Ct[64][100] fp32) -> float4 coalesced stores.
// ---------------------------------------------------------------------------
__global__ __launch_bounds__(256) void gemm_out96(
    const short* __restrict__ A, const short* __restrict__ B,
    const float* __restrict__ bias, float* __restrict__ C,
    int M, int N, int K)
{
    // As 2x[64][64], Bs 2x[96][64] shorts = 40960 B; epilogue Ct[64][100] fp32
    // (25600 B) reuses the same region.
    __shared__ __align__(16) short smem[2 * 4096 + 2 * 6144];
    short* As0 = smem;              // + b*4096
    short* Bs0 = smem + 2 * 4096;   // + b*6144

    const int t = threadIdx.x;
    const int w = t >> 6, l = t & 63;
    const int quad = l >> 4, lane16 = l & 15;
    const int m0 = blockIdx.y * 64, n0 = blockIdx.x * 96;
    const int wm = (w >> 1) * 32, wn = (w & 1) * 48;

    f32x4 acc[2][3];
#pragma unroll
    for (int i = 0; i < 2; ++i)
#pragma unroll
        for (int j = 0; j < 3; ++j) acc[i][j] = (f32x4){0.f, 0.f, 0.f, 0.f};

    const int NKI = K >> 6;   // 12

    auto stage = [&](int ki, int b) {
        short* Asb = As0 + b * 4096;
        short* Bsb = Bs0 + b * 6144;
#pragma unroll
        for (int i = 0; i < 5; ++i) {
            int c = i * 256 + t;              // 0..1279: 512 A + 768 B chunks
            if (c < 512) {
                int r = c >> 3, kc = c & 7;
                int g = kc ^ (r & 7);
#if defined(__HIP_DEVICE_COMPILE__) && __has_builtin(__builtin_amdgcn_global_load_lds)
                __builtin_amdgcn_global_load_lds(
                    (const __attribute__((address_space(1))) void*)(A + (size_t)(m0 + r) * K + ki * 64 + g * 8),
                    (__attribute__((address_space(3))) void*)(Asb + c * 8), 16, 0, 0);
#else
                *(short8*)(Asb + c * 8) = *(const short8*)(A + (size_t)(m0 + r) * K + ki * 64 + g * 8);
#endif
            } else {
                int cb = c - 512;             // 0..767
                int r = cb >> 3, kc = cb & 7;
                int g = kc ^ (r & 7);
#if defined(__HIP_DEVICE_COMPILE__) && __has_builtin(__builtin_amdgcn_global_load_lds)
                __builtin_amdgcn_global_load_lds(
                    (const __attribute__((address_space(1))) void*)(B + (size_t)(n0 + r) * K + ki * 64 + g * 8),
                    (__attribute__((address_space(3))) void*)(Bsb + cb * 8), 16, 0, 0);
#else
                *(short8*)(Bsb + cb * 8) = *(const short8*)(B + (size_t)(n0 + r) * K + ki * 64 + g * 8);
#endif
            }
        }
    };

    stage(0, 0);
    for (int kb = 0; kb < NKI; ++kb) {
        const int cur = kb & 1;
        __syncthreads();
        if (kb + 1 < NKI) stage(kb + 1, cur ^ 1);

        const short* Asb = As0 + cur * 4096;
        const short* Bsb = Bs0 + cur * 6144;
#pragma unroll
        for (int ks = 0; ks < 2; ++ks) {
            short8 af[2], bfr[3];
#pragma unroll
            for (int mt = 0; mt < 2; ++mt) {
                int row = wm + mt * 16 + lane16;
                int slot = (ks * 4 + quad) ^ (row & 7);
                af[mt] = *(const short8*)(Asb + row * 64 + slot * 8);
            }
#pragma unroll
            for (int nt = 0; nt < 3; ++nt) {
                int row = wn + nt * 16 + lane16;
                int slot = (ks * 4 + quad) ^ (row & 7);
                bfr[nt] = *(const short8*)(Bsb + row * 64 + slot * 8);
            }
#pragma unroll
            for (int mt = 0; mt < 2; ++mt)
#pragma unroll
                for (int nt = 0; nt < 3; ++nt)
                    acc[mt][nt] = __builtin_amdgcn_mfma_f32_16x16x32_bf16(
                        af[mt], bfr[nt], acc[mt][nt], 0, 0, 0);
        }
    }

    __syncthreads();   // K-loop LDS reads done
    float(*Ct)[100] = (float(*)[100])smem;   // 64x100 fp32, pad kills conflicts

#pragma unroll
    for (int nt = 0; nt < 3; ++nt) {
        int cl = wn + nt * 16 + lane16;
        float bv = bias[n0 + cl];
#pragma unroll
        for (int mt = 0; mt < 2; ++mt) {
#pragma unroll
            for (int r = 0; r < 4; ++r)
                Ct[wm + mt * 16 + quad * 4 + r][cl] = acc[mt][nt][r] + bv;
        }
    }
    __syncthreads();

    // coalesced flush: 1536 float4-chunks (row 0..63, colgroup 0..23)
#pragma unroll
    for (int pass = 0; pass < 6; ++pass) {
        int c = pass * 256 + t;
        int row = c / 24, cg = c - row * 24;
        float4 v = { Ct[row][cg * 4], Ct[row][cg * 4 + 1],
                     Ct[row][cg * 4 + 2], Ct[row][cg * 4 + 3] };
        *(float4*)(C + (size_t)(m0 + row) * N + n0 + cg * 4) = v;
    }
}

extern "C" void kernel_launch(void* const* d_in, const int* in_sizes, int n_in,
                              void* d_out, int out_size, void* d_ws, size_t ws_size,
                              hipStream_t stream) {
    const float* x    = (const float*)d_in[0];
    const float* Wqkv = (const float*)d_in[1];
    const float* bqkv = (const float*)d_in[2];
    const float* Wo   = (const float*)d_in[3];
    const float* bo   = (const float*)d_in[4];
    const int*   wptr = (const int*)d_in[5];

    float* out = (float*)d_out;

    short* xb     = (short*)d_ws;
    short* wqkvb  = xb     + (size_t)S_LEN * EMB;
    short* wob    = wqkvb  + (size_t)3 * EMB * EMB;
    short* qsplit = wob    + (size_t)EMB * EMB;          // Q|K row-major, V^T
    short* attn   = qsplit + (size_t)3 * NH * S_LEN * HD;

    dim3 blk(256);
    convert_all<<<dim3((NX4 + NW4 + NO4) / 1024), blk, 0, stream>>>(
        x, Wqkv, Wo, xb, wqkvb, wob);
    gemm_qkv<<<dim3(2304 / 96, S_LEN / 128), blk, 0, stream>>>(
        xb, wqkvb, bqkv, qsplit, S_LEN, 2304, EMB);
    attn_win<<<dim3(S_LEN / QT * NH), blk, 0, stream>>>(qsplit, wptr, attn);
    gemm_out96<<<dim3(EMB / 96, S_LEN / 64), blk, 0, stream>>>(
        attn, wob, bo, out, S_LEN, EMB, EMB);
}